// Round 8
// baseline (294.065 us; speedup 1.0000x reference)
//
#include <hip/hip_runtime.h>

#define T_GT 64
#define KP 2            // priors per thread
#define TPB 256
#define MAGIC 0x4D414731u   // != 0xAAAAAAAA poison, != 0

typedef unsigned int u32;
typedef unsigned long long u64;

// ---------------------------------------------------------------------------
// Single fused kernel. Thread = (b, KP consecutive priors).
// Phase 1: exact overlap screen. inter>0  <=>  gz>px0 && px1>gx && gw>py0 &&
//   py1>gy (positive-width boxes; IEEE sub sign is exact; product-underflow
//   pairs evaluate to q=+0.0 which is a no-op vs defaults). Mask built with t
//   descending => bit k == t, ctz-ascending visit preserves numpy first-index.
// Phase 2: full __f*_rn IoU only for overlapping pairs (~5%):
//   - match: pack (q_bits<<32)|(63-t), u64 max; init {q=0,t=0}.
//   - best_prior: LDS atomicMax of (q_bits<<32)|(~p) per wave per t; slot
//     init {q=0,p=0}. Both reproduce numpy argmax over the implicit zeros.
// Completion: block publishes 64 merged partials to ws, then release-stores
//   a MAGIC flag (agent scope). Block x==0 of each image spins on all flags,
//   acquire-fences, reduces partials, applies matches[best_prior[t]]=t
//   (ascending scan, last-wins dup semantics) and rewrites those rows.
// ---------------------------------------------------------------------------
__global__ void __launch_bounds__(256)
fused_all(const float4* __restrict__ priors,
          const float4* __restrict__ gt_boxes,
          const int* __restrict__ gt_labels,
          u64* __restrict__ part,        // (B, NG, 64) block partials
          u32* __restrict__ done,        // (B, NG) flags
          float* __restrict__ out_loc,   // (B, P, 4)
          float* __restrict__ out_lbl,   // (B, P) as float
          int P, int NG) {
    __shared__ float4 s_gt[T_GT];
    __shared__ int    s_lbl[T_GT];
    __shared__ u64    s_best[4][T_GT];
    __shared__ u32    s_p[T_GT];

    const int tid  = threadIdx.x;
    const int lane = tid & 63;
    const int wv   = tid >> 6;
    const int b    = blockIdx.y;
    const int tb   = blockIdx.x * TPB + tid;

    if (tid < T_GT) {
        s_gt[tid]  = gt_boxes[b * T_GT + tid];
        s_lbl[tid] = gt_labels[b * T_GT + tid];
    }
    s_best[wv][lane] = (u64)0xFFFFFFFFu;   // {q=+0.0, p=0} default
    __syncthreads();

    // load KP consecutive priors; precompute xyxy + area (ref op order)
    float px0[KP], py0[KP], px1[KP], py1[KP], pa[KP];
    float4 prr[KP];
    u32 pc[KP];
    #pragma unroll
    for (int j = 0; j < KP; ++j) {
        const int p = min(tb * KP + j, P - 1);  // clamp: dup of P-1 harmless
        pc[j] = (u32)p;
        const float4 pr = priors[p];
        prr[j] = pr;
        px0[j] = __fsub_rn(pr.x, __fmul_rn(0.5f, pr.z));
        py0[j] = __fsub_rn(pr.y, __fmul_rn(0.5f, pr.w));
        px1[j] = __fadd_rn(pr.x, __fmul_rn(0.5f, pr.z));
        py1[j] = __fadd_rn(pr.y, __fmul_rn(0.5f, pr.w));
        pa[j]  = __fmul_rn(__fsub_rn(px1[j], px0[j]), __fsub_rn(py1[j], py0[j]));
    }

    // ---- phase 1: overlap masks (t descending -> bit k == t) ----
    u32 mhi[KP], mlo[KP];
    #pragma unroll
    for (int j = 0; j < KP; ++j) { mhi[j] = 0; mlo[j] = 0; }

    #pragma unroll 8
    for (int t = 63; t >= 32; --t) {
        const float4 gb = s_gt[t];
        #pragma unroll
        for (int j = 0; j < KP; ++j) {
            const bool ov = (gb.z > px0[j]) & (px1[j] > gb.x) &
                            (gb.w > py0[j]) & (py1[j] > gb.y);
            mhi[j] = mhi[j] + mhi[j] + (ov ? 1u : 0u);
        }
    }
    #pragma unroll 8
    for (int t = 31; t >= 0; --t) {
        const float4 gb = s_gt[t];
        #pragma unroll
        for (int j = 0; j < KP; ++j) {
            const bool ov = (gb.z > px0[j]) & (px1[j] > gb.x) &
                            (gb.w > py0[j]) & (py1[j] > gb.y);
            mlo[j] = mlo[j] + mlo[j] + (ov ? 1u : 0u);
        }
    }

    // ---- phase 2: evaluate candidates only ----
    u64 mbest[KP];
    #pragma unroll
    for (int j = 0; j < KP; ++j) mbest[j] = 63u;   // {q=0, rt=63} == t 0

    #pragma unroll
    for (int j = 0; j < KP; ++j) {
        #pragma unroll
        for (int half = 0; half < 2; ++half) {
            u32 mask = half ? mhi[j] : mlo[j];
            const int tbase = half ? 32 : 0;
            while (mask) {                        // ascending t per lane
                const int t = tbase + __builtin_ctz(mask);
                mask &= mask - 1;
                const float4 gb = s_gt[t];
                const float gar = __fmul_rn(__fsub_rn(gb.z, gb.x),
                                            __fsub_rn(gb.w, gb.y));
                const float ltx = fmaxf(gb.x, px0[j]);
                const float lty = fmaxf(gb.y, py0[j]);
                const float rbx = fminf(gb.z, px1[j]);
                const float rby = fminf(gb.w, py1[j]);
                const float wx = fmaxf(__fsub_rn(rbx, ltx), 0.0f);
                const float wy = fmaxf(__fsub_rn(rby, lty), 0.0f);
                const float inter = __fmul_rn(wx, wy);
                const float uni = __fsub_rn(__fadd_rn(gar, pa[j]), inter);
                const float q = __fdiv_rn(inter, uni);    // IEEE f32 divide
                const u64 qh = (u64)__float_as_uint(q) << 32;
                const u64 mp = qh | (u32)(63 - t);
                if (mp > mbest[j]) mbest[j] = mp;
                atomicMax(&s_best[wv][t], qh | (u64)(0xFFFFFFFFu - pc[j]));
            }
        }
    }

    __syncthreads();
    if (tid < T_GT) {
        u64 m = s_best[0][tid];
        #pragma unroll
        for (int w = 1; w < 4; ++w) {
            const u64 v = s_best[w][tid];
            if (v > m) m = v;
        }
        part[((size_t)b * NG + blockIdx.x) * T_GT + tid] = m;
    }

    // ---- epilogue: per-prior match output ----
    #pragma unroll
    for (int j = 0; j < KP; ++j) {
        const int p = tb * KP + j;
        if (p < P) {
            const int   t_best = 63 - (int)(mbest[j] & 63u);
            const float q_best = __uint_as_float((u32)(mbest[j] >> 32));
            const int   lbl = (q_best < 0.5f) ? 0 : s_lbl[t_best];

            const float4 pr = prr[j];
            const float4 mb = s_gt[t_best];
            const float  bcx = (mb.x + mb.z) * 0.5f;
            const float  bcy = (mb.y + mb.w) * 0.5f;
            const float  bw  = mb.z - mb.x;
            const float  bh  = mb.w - mb.y;

            float4 loc;
            loc.x = (bcx - pr.x) / (0.1f * pr.z);
            loc.y = (bcy - pr.y) / (0.1f * pr.w);
            loc.z = logf(bw / pr.z) / 0.2f;
            loc.w = logf(bh / pr.w) / 0.2f;

            ((float4*)out_loc)[(size_t)b * P + p] = loc;
            out_lbl[(size_t)b * P + p] = (float)lbl;
        }
    }

    // ---- publish: all block stores ordered before release flag ----
    __syncthreads();
    if (tid == 0) {
        __threadfence();   // agent fence: flush this block's stores device-wide
        __hip_atomic_store(&done[b * NG + blockIdx.x], MAGIC,
                           __ATOMIC_RELEASE, __HIP_MEMORY_SCOPE_AGENT);
    }

    if (blockIdx.x != 0) return;

    // ---- finisher (one block per image): wait for all partials ----
    for (;;) {
        int ok = 1;
        for (int g = tid; g < NG; g += TPB)
            ok &= (__hip_atomic_load(&done[b * NG + g],
                                     __ATOMIC_ACQUIRE,
                                     __HIP_MEMORY_SCOPE_AGENT) == MAGIC);
        if (__syncthreads_and(ok)) break;
        __builtin_amdgcn_s_sleep(2);
    }
    __threadfence();   // acquire side: invalidate stale cache before reads

    // reduce NG partials per t (4-way independent loads to hide latency)
    const int t = tid & 63;
    const int w = tid >> 6;
    const size_t base = (size_t)b * NG * T_GT + t;
    u64 m = 0;
    int g = w;
    for (; g + 12 < NG; g += 16) {
        const u64 a0 = part[base + (size_t)g * T_GT];
        const u64 a1 = part[base + (size_t)(g + 4) * T_GT];
        const u64 a2 = part[base + (size_t)(g + 8) * T_GT];
        const u64 a3 = part[base + (size_t)(g + 12) * T_GT];
        u64 x = a0 > a1 ? a0 : a1;
        const u64 y = a2 > a3 ? a2 : a3;
        if (y > x) x = y;
        if (x > m) m = x;
    }
    for (; g < NG; g += 4) {
        const u64 v = part[base + (size_t)g * T_GT];
        if (v > m) m = v;
    }
    s_best[w][t] = m;
    __syncthreads();
    if (tid < T_GT) {
        m = s_best[0][t];
        #pragma unroll
        for (int i = 1; i < 4; ++i) {
            const u64 v = s_best[i][t];
            if (v > m) m = v;
        }
        s_p[t] = 0xFFFFFFFFu - (u32)(m & 0xFFFFFFFFull);
    }
    __syncthreads();
    if (tid >= T_GT) return;

    // matches[best_prior] = arange(T): numpy last-wins on duplicates
    const u32 p = s_p[tid];
    for (int u = tid + 1; u < T_GT; ++u)
        if (s_p[u] == p) return;

    const float4 pr = priors[p];
    const float4 mb = s_gt[tid];
    const float  bcx = (mb.x + mb.z) * 0.5f;
    const float  bcy = (mb.y + mb.w) * 0.5f;
    const float  bw  = mb.z - mb.x;
    const float  bh  = mb.w - mb.y;

    float4 loc;
    loc.x = (bcx - pr.x) / (0.1f * pr.z);
    loc.y = (bcy - pr.y) / (0.1f * pr.w);
    loc.z = logf(bw / pr.z) / 0.2f;
    loc.w = logf(bh / pr.w) / 0.2f;

    ((float4*)out_loc)[(size_t)b * P + p] = loc;
    out_lbl[(size_t)b * P + p] = (float)s_lbl[tid];
}

extern "C" void kernel_launch(void* const* d_in, const int* in_sizes, int n_in,
                              void* d_out, int out_size, void* d_ws, size_t ws_size,
                              hipStream_t stream) {
    const float4* priors    = (const float4*)d_in[0];   // (P, 4) f32
    const float4* gt_boxes  = (const float4*)d_in[1];   // (B, T, 4) f32
    const int*    gt_labels = (const int*)d_in[2];      // (B, T) i32

    const int P = in_sizes[0] / 4;
    const int B = in_sizes[2] / T_GT;

    float* out_loc = (float*)d_out;
    float* out_lbl = out_loc + (size_t)B * P * 4;

    const int NG = (P + TPB * KP - 1) / (TPB * KP);   // blocks per image (196)
    u64* part = (u64*)d_ws;                            // (B, NG, 64) u64
    u32* done = (u32*)((char*)d_ws + (size_t)B * NG * T_GT * sizeof(u64));

    // clear flags only (12.5 KB; partials are fully overwritten)
    hipMemsetAsync(done, 0, (size_t)B * NG * sizeof(u32), stream);

    dim3 g(NG, B);
    fused_all<<<g, TPB, 0, stream>>>(priors, gt_boxes, gt_labels, part, done,
                                     out_loc, out_lbl, P, NG);
}

// Round 9
// 121.252 us; speedup vs baseline: 2.4252x; 2.4252x over previous
//
#include <hip/hip_runtime.h>

#define T_GT 64
#define KP 2            // priors per thread
#define TPB 256

typedef unsigned int u32;
typedef unsigned long long u64;

// ---------------------------------------------------------------------------
// Single fused kernel, fence-free last-block finisher.
//
// Compute (round-7 core): thread = (b, KP consecutive priors).
//  Phase 1: exact overlap screen (inter>0 <=> 4 strict compares; IEEE sub
//    sign exact; underflow pairs give q=+0.0 == the defaults). Mask bit k==t;
//    ctz-ascending visit preserves numpy first-index tie-break.
//  Phase 2: full __f*_rn IoU for overlapping pairs only (~5%):
//    match: pack (q<<32)|(63-t) max; best_prior: LDS atomicMax of
//    (q<<32)|(~p) per wave per t. Defaults {q=0,t=0}/{q=0,p=0} == numpy
//    argmax over the implicit all-zero rows/cols.
//
// Cross-block protocol (NO device-scope fences — round-8 post-mortem:
// per-block buffer_wbl2 cost ~200 µs):
//  - part[] and ALL out rows stored with relaxed AGENT-scope stores
//    (write-through the coherent LLC; nothing dirty in per-XCD L2).
//  - release by hand: s_waitcnt vmcnt(0) per thread -> __syncthreads ->
//    ONE relaxed AGENT fetch_add ticket per block.
//  - ticket NG-1 (last block, all prior stores LLC-visible) becomes the
//    finisher: AGENT-loads all partials, reduces, applies
//    matches[best_prior[t]]=t (ascending scan = numpy last-wins) with AGENT
//    stores (LLC orders them after the owners' stores).
// ---------------------------------------------------------------------------
__global__ void __launch_bounds__(256)
fused_all(const float4* __restrict__ priors,
          const float4* __restrict__ gt_boxes,
          const int* __restrict__ gt_labels,
          u64* __restrict__ part,        // (B, NG, 64) block partials
          u32* __restrict__ cnt,         // (B) ticket counters, pre-zeroed
          float* __restrict__ out_loc,   // (B, P, 4)
          float* __restrict__ out_lbl,   // (B, P) as float
          int P, int NG) {
    __shared__ float4 s_gt[T_GT];
    __shared__ float  s_ga[T_GT];
    __shared__ int    s_lbl[T_GT];
    __shared__ u64    s_best[4][T_GT];
    __shared__ u32    s_p[T_GT];
    __shared__ u32    s_rank;

    const int tid  = threadIdx.x;
    const int lane = tid & 63;
    const int wv   = tid >> 6;
    const int b    = blockIdx.y;
    const int tb   = blockIdx.x * TPB + tid;

    if (tid < T_GT) {
        const float4 gb = gt_boxes[b * T_GT + tid];
        s_gt[tid]  = gb;
        s_ga[tid]  = __fmul_rn(__fsub_rn(gb.z, gb.x), __fsub_rn(gb.w, gb.y));
        s_lbl[tid] = gt_labels[b * T_GT + tid];
    }
    s_best[wv][lane] = (u64)0xFFFFFFFFu;   // {q=+0.0, p=0} default
    __syncthreads();

    // load KP consecutive priors; precompute xyxy + area (ref op order)
    float px0[KP], py0[KP], px1[KP], py1[KP], pa[KP];
    float4 prr[KP];
    u32 pc[KP];
    #pragma unroll
    for (int j = 0; j < KP; ++j) {
        const int p = min(tb * KP + j, P - 1);  // clamp: dup of P-1 harmless
        pc[j] = (u32)p;
        const float4 pr = priors[p];
        prr[j] = pr;
        px0[j] = __fsub_rn(pr.x, __fmul_rn(0.5f, pr.z));
        py0[j] = __fsub_rn(pr.y, __fmul_rn(0.5f, pr.w));
        px1[j] = __fadd_rn(pr.x, __fmul_rn(0.5f, pr.z));
        py1[j] = __fadd_rn(pr.y, __fmul_rn(0.5f, pr.w));
        pa[j]  = __fmul_rn(__fsub_rn(px1[j], px0[j]), __fsub_rn(py1[j], py0[j]));
    }

    // ---- phase 1: overlap masks (t descending -> bit k == t) ----
    u32 mhi[KP], mlo[KP];
    #pragma unroll
    for (int j = 0; j < KP; ++j) { mhi[j] = 0; mlo[j] = 0; }

    #pragma unroll 8
    for (int t = 63; t >= 32; --t) {
        const float4 gb = s_gt[t];
        #pragma unroll
        for (int j = 0; j < KP; ++j) {
            const bool ov = (gb.z > px0[j]) & (px1[j] > gb.x) &
                            (gb.w > py0[j]) & (py1[j] > gb.y);
            mhi[j] = mhi[j] + mhi[j] + (ov ? 1u : 0u);
        }
    }
    #pragma unroll 8
    for (int t = 31; t >= 0; --t) {
        const float4 gb = s_gt[t];
        #pragma unroll
        for (int j = 0; j < KP; ++j) {
            const bool ov = (gb.z > px0[j]) & (px1[j] > gb.x) &
                            (gb.w > py0[j]) & (py1[j] > gb.y);
            mlo[j] = mlo[j] + mlo[j] + (ov ? 1u : 0u);
        }
    }

    // ---- phase 2: evaluate candidates only ----
    u64 mbest[KP];
    #pragma unroll
    for (int j = 0; j < KP; ++j) mbest[j] = 63u;   // {q=0, rt=63} == t 0

    #pragma unroll
    for (int j = 0; j < KP; ++j) {
        #pragma unroll
        for (int half = 0; half < 2; ++half) {
            u32 mask = half ? mhi[j] : mlo[j];
            const int tbase = half ? 32 : 0;
            while (mask) {                        // ascending t per lane
                const int t = tbase + __builtin_ctz(mask);
                mask &= mask - 1;
                const float4 gb  = s_gt[t];
                const float  gar = s_ga[t];
                const float ltx = fmaxf(gb.x, px0[j]);
                const float lty = fmaxf(gb.y, py0[j]);
                const float rbx = fminf(gb.z, px1[j]);
                const float rby = fminf(gb.w, py1[j]);
                const float wx = fmaxf(__fsub_rn(rbx, ltx), 0.0f);
                const float wy = fmaxf(__fsub_rn(rby, lty), 0.0f);
                const float inter = __fmul_rn(wx, wy);
                const float uni = __fsub_rn(__fadd_rn(gar, pa[j]), inter);
                const float q = __fdiv_rn(inter, uni);    // IEEE f32 divide
                const u64 qh = (u64)__float_as_uint(q) << 32;
                const u64 mp = qh | (u32)(63 - t);
                if (mp > mbest[j]) mbest[j] = mp;
                atomicMax(&s_best[wv][t], qh | (u64)(0xFFFFFFFFu - pc[j]));
            }
        }
    }

    __syncthreads();
    if (tid < T_GT) {
        u64 m = s_best[0][tid];
        #pragma unroll
        for (int w = 1; w < 4; ++w) {
            const u64 v = s_best[w][tid];
            if (v > m) m = v;
        }
        __hip_atomic_store(&part[((size_t)b * NG + blockIdx.x) * T_GT + tid],
                           m, __ATOMIC_RELAXED, __HIP_MEMORY_SCOPE_AGENT);
    }

    // ---- epilogue: per-prior match output (AGENT stores -> LLC) ----
    #pragma unroll
    for (int j = 0; j < KP; ++j) {
        const int p = tb * KP + j;
        if (p < P) {
            const int   t_best = 63 - (int)(mbest[j] & 63u);
            const float q_best = __uint_as_float((u32)(mbest[j] >> 32));
            const int   lbl = (q_best < 0.5f) ? 0 : s_lbl[t_best];

            const float4 pr = prr[j];
            const float4 mb = s_gt[t_best];
            const float  bcx = (mb.x + mb.z) * 0.5f;
            const float  bcy = (mb.y + mb.w) * 0.5f;
            const float  bw  = mb.z - mb.x;
            const float  bh  = mb.w - mb.y;

            const float lx = (bcx - pr.x) / (0.1f * pr.z);
            const float ly = (bcy - pr.y) / (0.1f * pr.w);
            const float lz = logf(bw / pr.z) / 0.2f;
            const float lw = logf(bh / pr.w) / 0.2f;

            u64* rowp = (u64*)(out_loc + ((size_t)b * P + p) * 4);
            const u64 lo = ((u64)__float_as_uint(ly) << 32) | __float_as_uint(lx);
            const u64 hi = ((u64)__float_as_uint(lw) << 32) | __float_as_uint(lz);
            __hip_atomic_store(&rowp[0], lo, __ATOMIC_RELAXED, __HIP_MEMORY_SCOPE_AGENT);
            __hip_atomic_store(&rowp[1], hi, __ATOMIC_RELAXED, __HIP_MEMORY_SCOPE_AGENT);
            __hip_atomic_store((u32*)(out_lbl + (size_t)b * P + p),
                               __float_as_uint((float)lbl),
                               __ATOMIC_RELAXED, __HIP_MEMORY_SCOPE_AGENT);
        }
    }

    // ---- hand-rolled release + last-block ticket (no fences, no wbl2) ----
    asm volatile("s_waitcnt vmcnt(0)" ::: "memory");  // stores acked at LLC
    __syncthreads();
    if (tid == 0)
        s_rank = __hip_atomic_fetch_add(&cnt[b], 1u, __ATOMIC_RELAXED,
                                        __HIP_MEMORY_SCOPE_AGENT);
    __syncthreads();
    if (s_rank != (u32)(NG - 1)) return;

    // ---- finisher (last block of image b): reduce NG partials per t ----
    const int t = tid & 63;
    const int w = tid >> 6;
    const size_t base = (size_t)b * NG * T_GT + t;
    u64 m = 0;
    int g = w;
    for (; g + 12 < NG; g += 16) {      // 4 independent AGENT loads in flight
        const u64 a0 = __hip_atomic_load(&part[base + (size_t)g * T_GT],
                                         __ATOMIC_RELAXED, __HIP_MEMORY_SCOPE_AGENT);
        const u64 a1 = __hip_atomic_load(&part[base + (size_t)(g + 4) * T_GT],
                                         __ATOMIC_RELAXED, __HIP_MEMORY_SCOPE_AGENT);
        const u64 a2 = __hip_atomic_load(&part[base + (size_t)(g + 8) * T_GT],
                                         __ATOMIC_RELAXED, __HIP_MEMORY_SCOPE_AGENT);
        const u64 a3 = __hip_atomic_load(&part[base + (size_t)(g + 12) * T_GT],
                                         __ATOMIC_RELAXED, __HIP_MEMORY_SCOPE_AGENT);
        u64 x = a0 > a1 ? a0 : a1;
        const u64 y = a2 > a3 ? a2 : a3;
        if (y > x) x = y;
        if (x > m) m = x;
    }
    for (; g < NG; g += 4) {
        const u64 v = __hip_atomic_load(&part[base + (size_t)g * T_GT],
                                        __ATOMIC_RELAXED, __HIP_MEMORY_SCOPE_AGENT);
        if (v > m) m = v;
    }
    s_best[w][t] = m;                   // reuse (safe after syncthreads)
    __syncthreads();
    if (tid < T_GT) {
        m = s_best[0][t];
        #pragma unroll
        for (int i = 1; i < 4; ++i) {
            const u64 v = s_best[i][t];
            if (v > m) m = v;
        }
        s_p[t] = 0xFFFFFFFFu - (u32)(m & 0xFFFFFFFFull);
    }
    __syncthreads();
    if (tid >= T_GT) return;

    // matches[best_prior] = arange(T): numpy last-wins on duplicates
    const u32 p = s_p[tid];
    for (int u = tid + 1; u < T_GT; ++u)
        if (s_p[u] == p) return;

    const float4 pr = priors[p];
    const float4 mb = s_gt[tid];
    const float  bcx = (mb.x + mb.z) * 0.5f;
    const float  bcy = (mb.y + mb.w) * 0.5f;
    const float  bw  = mb.z - mb.x;
    const float  bh  = mb.w - mb.y;

    const float lx = (bcx - pr.x) / (0.1f * pr.z);
    const float ly = (bcy - pr.y) / (0.1f * pr.w);
    const float lz = logf(bw / pr.z) / 0.2f;
    const float lw = logf(bh / pr.w) / 0.2f;

    u64* rowp = (u64*)(out_loc + ((size_t)b * P + p) * 4);
    const u64 lo = ((u64)__float_as_uint(ly) << 32) | __float_as_uint(lx);
    const u64 hi = ((u64)__float_as_uint(lw) << 32) | __float_as_uint(lz);
    __hip_atomic_store(&rowp[0], lo, __ATOMIC_RELAXED, __HIP_MEMORY_SCOPE_AGENT);
    __hip_atomic_store(&rowp[1], hi, __ATOMIC_RELAXED, __HIP_MEMORY_SCOPE_AGENT);
    __hip_atomic_store((u32*)(out_lbl + (size_t)b * P + p),
                       __float_as_uint((float)s_lbl[tid]),
                       __ATOMIC_RELAXED, __HIP_MEMORY_SCOPE_AGENT);
}

extern "C" void kernel_launch(void* const* d_in, const int* in_sizes, int n_in,
                              void* d_out, int out_size, void* d_ws, size_t ws_size,
                              hipStream_t stream) {
    const float4* priors    = (const float4*)d_in[0];   // (P, 4) f32
    const float4* gt_boxes  = (const float4*)d_in[1];   // (B, T, 4) f32
    const int*    gt_labels = (const int*)d_in[2];      // (B, T) i32

    const int P = in_sizes[0] / 4;
    const int B = in_sizes[2] / T_GT;

    float* out_loc = (float*)d_out;
    float* out_lbl = out_loc + (size_t)B * P * 4;

    const int NG = (P + TPB * KP - 1) / (TPB * KP);   // blocks per image (196)
    u64* part = (u64*)d_ws;                            // (B, NG, 64) u64
    u32* cnt  = (u32*)((char*)d_ws + (size_t)B * NG * T_GT * sizeof(u64));

    // zero the B ticket counters only (64 bytes)
    hipMemsetAsync(cnt, 0, (size_t)B * sizeof(u32), stream);

    dim3 g(NG, B);
    fused_all<<<g, TPB, 0, stream>>>(priors, gt_boxes, gt_labels, part, cnt,
                                     out_loc, out_lbl, P, NG);
}